// Round 1
// baseline (685.862 us; speedup 1.0000x reference)
//
#include <hip/hip_runtime.h>

#define Bsz  2048
#define Tlen 512
#define Din  32
#define Hd   64

typedef _Float16 half8 __attribute__((ext_vector_type(8)));
typedef float    f32x4 __attribute__((ext_vector_type(4)));

// LDS h-tile row stride in f16 elems: 72 -> 144B rows, keeps ds_read_b128 16B-aligned
#define HS 72

__device__ __forceinline__ float sigm(float x) {
    return __builtin_amdgcn_rcpf(1.0f + __builtin_amdgcn_exp2f(-1.442695041f * x));
}
__device__ __forceinline__ float tanh_(float x) {
    return 2.0f * __builtin_amdgcn_rcpf(1.0f + __builtin_amdgcn_exp2f(-2.885390082f * x)) - 1.0f;
}
__device__ __forceinline__ half8 load8(const float* p) {
    half8 r;
#pragma unroll
    for (int j = 0; j < 8; ++j) r[j] = (_Float16)p[j];
    return r;
}

#define MFMA(a, b, c) __builtin_amdgcn_mfma_f32_16x16x32_f16((a), (b), (c), 0, 0, 0)

__global__ __launch_bounds__(512, 2)
void gru_fused(const float* __restrict__ x,
               const float* __restrict__ Wih0, const float* __restrict__ Whh0,
               const float* __restrict__ bih0, const float* __restrict__ bhh0,
               const float* __restrict__ Wih1, const float* __restrict__ Whh1,
               const float* __restrict__ bih1, const float* __restrict__ bhh1,
               const float* __restrict__ fcw,  const float* __restrict__ fcb,
               float* __restrict__ out)
{
    // double-buffered h tiles (f16, MFMA A-operand staging)
    __shared__ _Float16 h1b[2][16][HS];
    __shared__ _Float16 h2b[2][16][HS];
    __shared__ float hfin[8][Hd];

    const int tid  = threadIdx.x;
    const int lane = tid & 63;
    const int wave = tid >> 6;
    const int grp  = wave >> 2;            // 0 = layer1 waves, 1 = layer2 waves
    const int wg   = wave & 3;             // which 16 gate-cols this wave owns
    const int m    = lane & 15;            // A-frag row (batch)
    const int quad = lane >> 4;            // k-chunk (A/B), row-group (C/D)
    const int col  = (wg << 4) + m;        // gate/h column 0..63
    const int b0   = blockIdx.x << 3;      // 8 batches per block

    // zero-init LDS state (h[-1] = 0)
    for (int idx = tid; idx < 2 * 16 * HS; idx += 512) {
        (&h1b[0][0][0])[idx] = (_Float16)0.f;
        (&h2b[0][0][0])[idx] = (_Float16)0.f;
    }

    // ---- persistent weight B-fragments in VGPRs (B[k][n] = W[n][k]) ----
    // wx: input-side (L1: Wih0 K=32 -> wx[0][gt] only; L2: Wih1 K=64 -> both kb)
    // wh: hidden-side (K=64, 2 k-blocks)
    half8 wx[2][3], wh[2][3];
    float brz0, brz1, bin_, bhn_;

    if (grp == 0) {
#pragma unroll
        for (int gt = 0; gt < 3; ++gt) {
            const int g = gt * 64 + col;
            wx[0][gt] = load8(Wih0 + g * Din + quad * 8);
#pragma unroll
            for (int kb = 0; kb < 2; ++kb)
                wh[kb][gt] = load8(Whh0 + g * Hd + kb * 32 + quad * 8);
        }
        brz0 = bih0[col] + bhh0[col];
        brz1 = bih0[64 + col] + bhh0[64 + col];
        bin_ = bih0[128 + col];
        bhn_ = bhh0[128 + col];
    } else {
#pragma unroll
        for (int gt = 0; gt < 3; ++gt) {
            const int g = gt * 64 + col;
#pragma unroll
            for (int kb = 0; kb < 2; ++kb) {
                wx[kb][gt] = load8(Wih1 + g * Hd + kb * 32 + quad * 8);
                wh[kb][gt] = load8(Whh1 + g * Hd + kb * 32 + quad * 8);
            }
        }
        brz0 = bih1[col] + bhh1[col];
        brz1 = bih1[64 + col] + bhh1[64 + col];
        bin_ = bih1[128 + col];
        bhn_ = bhh1[128 + col];
    }

    float hst[4] = {0.f, 0.f, 0.f, 0.f};   // C-layout state: rows quad*4+r, this col
    __syncthreads();

    // pipelined recurrence: iter i -> L1 computes h1[i], L2 computes h2[i-1]
    for (int i = 0; i <= Tlen; ++i) {
        const int rb = (i + 1) & 1;        // read buffer  = (i-1)&1
        const int wb = i & 1;              // write buffer
        const bool act = (grp == 0) ? (i < Tlen) : (i >= 1);
        if (act) {
            f32x4 ar = {0,0,0,0}, az = {0,0,0,0}, anx = {0,0,0,0}, anh = {0,0,0,0};
            half8 ah0, ah1;
            if (grp == 0) {
                half8 ax;
                if (m < 8) {
                    const float* xp = x + ((size_t)(b0 + m) * Tlen + i) * Din + quad * 8;
#pragma unroll
                    for (int j = 0; j < 8; ++j) ax[j] = (_Float16)xp[j];
                } else {
#pragma unroll
                    for (int j = 0; j < 8; ++j) ax[j] = (_Float16)0.f;  // ghost rows
                }
                ah0 = *(const half8*)&h1b[rb][m][quad * 8];
                ah1 = *(const half8*)&h1b[rb][m][32 + quad * 8];
                ar  = MFMA(ax, wx[0][0], ar);
                az  = MFMA(ax, wx[0][1], az);
                anx = MFMA(ax, wx[0][2], anx);
            } else {
                half8 ax0 = *(const half8*)&h1b[rb][m][quad * 8];       // h1[i-1]
                half8 ax1 = *(const half8*)&h1b[rb][m][32 + quad * 8];
                ah0 = *(const half8*)&h2b[rb][m][quad * 8];             // h2[i-2]
                ah1 = *(const half8*)&h2b[rb][m][32 + quad * 8];
                ar  = MFMA(ax0, wx[0][0], ar);  ar  = MFMA(ax1, wx[1][0], ar);
                az  = MFMA(ax0, wx[0][1], az);  az  = MFMA(ax1, wx[1][1], az);
                anx = MFMA(ax0, wx[0][2], anx); anx = MFMA(ax1, wx[1][2], anx);
            }
            ar  = MFMA(ah0, wh[0][0], ar);  ar  = MFMA(ah1, wh[1][0], ar);
            az  = MFMA(ah0, wh[0][1], az);  az  = MFMA(ah1, wh[1][1], az);
            anh = MFMA(ah0, wh[0][2], anh); anh = MFMA(ah1, wh[1][2], anh);

            _Float16* dst = (grp == 0) ? &h1b[wb][0][0] : &h2b[wb][0][0];
#pragma unroll
            for (int r = 0; r < 4; ++r) {
                float rr = sigm(ar[r] + brz0);
                float zz = sigm(az[r] + brz1);
                float nn = tanh_(anx[r] + bin_ + rr * (anh[r] + bhn_));
                hst[r] = (1.f - zz) * nn + zz * hst[r];
                dst[(quad * 4 + r) * HS + col] = (_Float16)hst[r];
            }
        }
        __syncthreads();   // write(i) -> read(i+1); also protects WAR across buffers
    }

    // hst of layer-2 waves now holds h2[T-1]; FC head
    if (grp == 1 && quad < 2) {
#pragma unroll
        for (int r = 0; r < 4; ++r) hfin[quad * 4 + r][col] = hst[r];
    }
    __syncthreads();
    if (tid < 8) {
        float acc = fcb[0];
        for (int c = 0; c < Hd; ++c) acc += hfin[tid][c] * fcw[c];
        out[b0 + tid] = acc;
    }
}

extern "C" void kernel_launch(void* const* d_in, const int* in_sizes, int n_in,
                              void* d_out, int out_size, void* d_ws, size_t ws_size,
                              hipStream_t stream) {
    gru_fused<<<dim3(Bsz / 8), dim3(512), 0, stream>>>(
        (const float*)d_in[0],
        (const float*)d_in[1], (const float*)d_in[2],
        (const float*)d_in[3], (const float*)d_in[4],
        (const float*)d_in[5], (const float*)d_in[6],
        (const float*)d_in[7], (const float*)d_in[8],
        (const float*)d_in[9], (const float*)d_in[10],
        (float*)d_out);
}